// Round 2
// baseline (629.984 us; speedup 1.0000x reference)
//
#include <hip/hip_runtime.h>

typedef unsigned short ushort_t;
typedef unsigned char uchar_t;
typedef __attribute__((ext_vector_type(8))) __bf16 bf16x8;
typedef __attribute__((ext_vector_type(4))) float f32x4;
typedef __attribute__((ext_vector_type(8))) unsigned short u16x8;
typedef __attribute__((ext_vector_type(8))) int i32x8;

#define NB 32
#define TT 12
#define NNODE 1024
#define FF 64
#define OO 64
#define TO 768   // TT*OO

#define SCL_ONE 127   // e8m0 2^0
#define SCL_E   118   // e8m0 2^-9  (E stored pre-scaled by 2^9)

__device__ __forceinline__ unsigned short f2bf(float f) {
    unsigned u = __float_as_uint(f);
    u += 0x7FFFu + ((u >> 16) & 1u);           // RNE
    return (unsigned short)(u >> 16);
}
__device__ __forceinline__ float bf2f(unsigned short h) {
    return __uint_as_float(((unsigned)h) << 16);
}
__device__ __forceinline__ unsigned char f2fp8(float f) {
    return (unsigned char)(__builtin_amdgcn_cvt_pk_fp8_f32(f, f, 0, false) & 0xff);
}

// async global->LDS, 16B/lane; LDS dest = wave-uniform base + lane*16
__device__ __forceinline__ void gload16(const void* g, void* l) {
    __builtin_amdgcn_global_load_lds(
        (const __attribute__((address_space(1))) unsigned int*)g,
        (__attribute__((address_space(3))) unsigned int*)l, 16, 0, 0);
}

// ---------------------------------------------------------------- lambda init
__global__ void k_init(unsigned* lam) {
    if (threadIdx.x < NB) lam[threadIdx.x] = 0x3F800000u;  // 1.0f clamp
}

// ------------------------------------------------- lambda = max row-sum of A
__global__ __launch_bounds__(256) void k_rowmax(const float* __restrict__ A,
                                                unsigned* __restrict__ lam) {
    const int b = blockIdx.x >> 4;
    const int chunk = blockIdx.x & 15;
    const int w = threadIdx.x >> 6, lane = threadIdx.x & 63;
    const float* Ab = A + (size_t)b * NNODE * NNODE;
    float mx = 0.0f;
    for (int r = 0; r < 16; ++r) {
        const float* rp = Ab + (size_t)(chunk * 64 + w * 16 + r) * NNODE;
        float s = 0.0f;
#pragma unroll
        for (int j = 0; j < 16; ++j) s += rp[lane + j * 64];
#pragma unroll
        for (int off = 32; off > 0; off >>= 1) s += __shfl_down(s, off, 64);
        if (lane == 0) mx = fmaxf(mx, s);
    }
    if (lane == 0) atomicMax(&lam[b], __float_as_uint(mx));
}

// ----------------- E8[b][n][m] = fp8( A * 2^10 / lam )   (E = 2A/lam, x2^9)
__global__ __launch_bounds__(256) void k_escale(const float* __restrict__ A,
                                                const unsigned* __restrict__ lam,
                                                uchar_t* __restrict__ E8) {
    const size_t idx = ((size_t)blockIdx.x * 256 + threadIdx.x) * 8;
    const int b = (int)(idx >> 20);
    const float scl = 1024.0f / __uint_as_float(lam[b]);
    const float4 v0 = *(const float4*)(A + idx);
    const float4 v1 = *(const float4*)(A + idx + 4);
    unsigned lo = 0, hi = 0;
    lo = (unsigned)__builtin_amdgcn_cvt_pk_fp8_f32(v0.x * scl, v0.y * scl, (int)lo, false);
    lo = (unsigned)__builtin_amdgcn_cvt_pk_fp8_f32(v0.z * scl, v0.w * scl, (int)lo, true);
    hi = (unsigned)__builtin_amdgcn_cvt_pk_fp8_f32(v1.x * scl, v1.y * scl, (int)hi, false);
    hi = (unsigned)__builtin_amdgcn_cvt_pk_fp8_f32(v1.z * scl, v1.w * scl, (int)hi, true);
    uint2 pk; pk.x = lo; pk.y = hi;
    *(uint2*)(E8 + idx) = pk;
}

// ------------------------- Theta [3][64 f][64 o] fp32 -> Tht [3][64 o][64 f] bf16
__global__ void k_theta(const float* __restrict__ Th, ushort_t* __restrict__ Tht) {
    int tid = blockIdx.x * 256 + threadIdx.x;
    if (tid < 3 * 64 * 64) {
        int k = tid >> 12, rem = tid & 4095, o = rem >> 6, f = rem & 63;
        Tht[tid] = f2bf(Th[(k << 12) + (f << 6) + o]);
    }
}

// ----------------- feature transform: Rk = x@Theta_k  (bf16 MFMA / fp32 acc)
// writes: Pb[b,t,n,o]     = bf16(R0 - R2)      (row-major)
//         Qc[b][c][n]     = bf16(R1 - 2*R2)    (col-major, k=n contiguous)
//         R2f8[b][c][n]   = fp8(R2)            (col-major)
__global__ __launch_bounds__(256) void k_feature(const float* __restrict__ x,
                                                 const ushort_t* __restrict__ Tht,
                                                 ushort_t* __restrict__ Pb,
                                                 ushort_t* __restrict__ Qc,
                                                 uchar_t* __restrict__ R2f8) {
    __shared__ ushort_t xt[128 * 64];
    __shared__ ushort_t tb[64 * 136];   // bf16 transpose buf; reused as char (64*144)
    const int n0 = blockIdx.x * 128;
    const int t = blockIdx.y;
    const int b = blockIdx.z;
    const int tid = threadIdx.x;
    const int w = tid >> 6, lane = tid & 63, quad = lane >> 4, l15 = lane & 15;

    const float* xb = x + (((size_t)b * TT + t) * NNODE + n0) * FF;
#pragma unroll
    for (int i = 0; i < 8; ++i) {
        int q = i * 256 + tid;
        int row = q >> 4, fq = q & 15;
        const float4 v = *(const float4*)(xb + row * 64 + fq * 4);
        uint2 pk;
        pk.x = (unsigned)f2bf(v.x) | ((unsigned)f2bf(v.y) << 16);
        pk.y = (unsigned)f2bf(v.z) | ((unsigned)f2bf(v.w) << 16);
        *(uint2*)(xt + row * 64 + fq * 4) = pk;
    }
    __syncthreads();

    bf16x8 af[2][2];
#pragma unroll
    for (int rb = 0; rb < 2; ++rb)
#pragma unroll
        for (int ks = 0; ks < 2; ++ks)
            af[rb][ks] = *(const bf16x8*)(xt + (w * 32 + rb * 16 + l15) * 64 + ks * 32 + quad * 8);

    f32x4 acc[3][2][4];
#pragma unroll
    for (int k = 0; k < 3; ++k)
#pragma unroll
        for (int rb = 0; rb < 2; ++rb)
#pragma unroll
            for (int cb = 0; cb < 4; ++cb)
                acc[k][rb][cb] = (f32x4){0.f, 0.f, 0.f, 0.f};

#pragma unroll
    for (int k = 0; k < 3; ++k)
#pragma unroll
        for (int ks = 0; ks < 2; ++ks)
#pragma unroll
            for (int cb = 0; cb < 4; ++cb) {
                bf16x8 bfr = *(const bf16x8*)(Tht + ((size_t)(k * 64 + cb * 16 + l15)) * 64 + ks * 32 + quad * 8);
#pragma unroll
                for (int rb = 0; rb < 2; ++rb)
                    acc[k][rb][cb] = __builtin_amdgcn_mfma_f32_16x16x32_bf16(af[rb][ks], bfr, acc[k][rb][cb], 0, 0, 0);
            }

    // P = R0 - R2, row-major
    ushort_t* Pbb = Pb + (((size_t)b * TT + t) * NNODE + n0) * OO;
#pragma unroll
    for (int rb = 0; rb < 2; ++rb)
#pragma unroll
        for (int cb = 0; cb < 4; ++cb)
#pragma unroll
            for (int r = 0; r < 4; ++r) {
                int n = w * 32 + rb * 16 + quad * 4 + r;
                int o = cb * 16 + l15;
                Pbb[(size_t)n * OO + o] = f2bf(acc[0][rb][cb][r] - acc[2][rb][cb][r]);
            }

    // pass 0: Q = R1 - 2*R2 (bf16, transposed); pass 1: R2 (fp8, transposed)
    {   // Q pass
#pragma unroll
        for (int rb = 0; rb < 2; ++rb)
#pragma unroll
            for (int cb = 0; cb < 4; ++cb)
#pragma unroll
                for (int r = 0; r < 4; ++r) {
                    int nl = w * 32 + rb * 16 + quad * 4 + r;
                    int o = cb * 16 + l15;
                    tb[o * 136 + nl] = f2bf(acc[1][rb][cb][r] - 2.0f * acc[2][rb][cb][r]);
                }
        __syncthreads();
        int o = tid >> 2, seg = tid & 3;
        ushort_t* drow = Qc + ((size_t)b * TO + t * 64 + o) * NNODE + n0 + seg * 32;
        const ushort_t* srow = tb + o * 136 + seg * 32;
#pragma unroll
        for (int i = 0; i < 4; ++i)
            *(u16x8*)(drow + i * 8) = *(const u16x8*)(srow + i * 8);
        __syncthreads();
    }
    {   // R2 fp8 pass
        char* tbc = (char*)tb;   // stride 144 bytes (16B aligned rows)
#pragma unroll
        for (int rb = 0; rb < 2; ++rb)
#pragma unroll
            for (int cb = 0; cb < 4; ++cb)
#pragma unroll
                for (int r = 0; r < 4; ++r) {
                    int nl = w * 32 + rb * 16 + quad * 4 + r;
                    int o = cb * 16 + l15;
                    tbc[o * 144 + nl] = (char)f2fp8(acc[2][rb][cb][r]);
                }
        __syncthreads();
        int o = tid >> 2, seg = tid & 3;
        uchar_t* drow = R2f8 + ((size_t)b * TO + t * 64 + o) * NNODE + n0 + seg * 32;
        const char* srow = tbc + o * 144 + seg * 32;
        *(int4*)(drow) = *(const int4*)(srow);
        *(int4*)(drow + 16) = *(const int4*)(srow + 16);
    }
}

// ------------------------------------------------------------- MX-fp8 GEMM
// D[r][c] = sum_k Aop[b][r][k] * Bop[b][c][k], both fp8 k-contiguous,
// HW descale 2^-9 total (E operand stored x2^9).
// MODE 1 (Z build):  r=c-idx(768), c=n.  A=R2f8, B=E8.
//    z = Q[c][n] + 2*D;  Zf8[c][n]=fp8(z);  Pb[b,t,n,o] -= z  (bf16 RMW)
// MODE 2 (output):   r=n, c=c-idx(768).    A=E8, B=Zf8.
//    out = relu(bf16(Pb) + D)   (Pb already holds P - Z)
template <int MODE>
__global__ __launch_bounds__(256) void k_gemm8(const uchar_t* __restrict__ Aop, size_t aBS,
                                               const uchar_t* __restrict__ Bop, size_t bBS,
                                               const ushort_t* __restrict__ Qc,
                                               uchar_t* __restrict__ Zf8,
                                               ushort_t* __restrict__ Pbp,
                                               float* __restrict__ outp) {
    __shared__ __align__(16) uchar_t At[128 * 128];
    __shared__ __align__(16) uchar_t Bt[128 * 128];
    const int b = blockIdx.z;
    const int m0 = blockIdx.x * 128, n0 = blockIdx.y * 128;
    const int tid = threadIdx.x;
    const int w = tid >> 6, lane = tid & 63, quad = lane >> 4, l15 = lane & 15;
    const int wr = w >> 1, wc = w & 1;
    const uchar_t* Ab = Aop + (size_t)b * aBS + (size_t)m0 * NNODE;
    const uchar_t* Bb = Bop + (size_t)b * bBS + (size_t)n0 * NNODE;

    // staging slots: 16KB per tile, XOR-swizzled 16B chunks (phys = log ^ (row&7))
    int ldso[4];
    size_t goff[4];
#pragma unroll
    for (int i = 0; i < 4; ++i) {
        int slot = i * 256 + tid;
        int row = slot >> 3;
        int lc = (slot & 7) ^ (row & 7);
        ldso[i] = slot * 16;
        goff[i] = (size_t)row * NNODE + lc * 16;
    }

    f32x4 acc[4][4];
#pragma unroll
    for (int i = 0; i < 4; ++i)
#pragma unroll
        for (int j = 0; j < 4; ++j) acc[i][j] = (f32x4){0.f, 0.f, 0.f, 0.f};

    for (int kk = 0; kk < 8; ++kk) {
        const int k0 = kk << 7;
#pragma unroll
        for (int i = 0; i < 4; ++i) {
            gload16(Ab + k0 + goff[i], At + ldso[i]);
            gload16(Bb + k0 + goff[i], Bt + ldso[i]);
        }
        __syncthreads();
        i32x8 af[4], bfr[4];
#pragma unroll
        for (int i = 0; i < 4; ++i) {
            const int m = wr * 64 + i * 16 + l15;
            const int n = wc * 64 + i * 16 + l15;
            const int4 alo = *(const int4*)(At + m * 128 + (((quad << 1)) ^ (m & 7)) * 16);
            const int4 ahi = *(const int4*)(At + m * 128 + (((quad << 1) | 1) ^ (m & 7)) * 16);
            const int4 blo = *(const int4*)(Bt + n * 128 + (((quad << 1)) ^ (n & 7)) * 16);
            const int4 bhi = *(const int4*)(Bt + n * 128 + (((quad << 1) | 1) ^ (n & 7)) * 16);
            af[i] = (i32x8){alo.x, alo.y, alo.z, alo.w, ahi.x, ahi.y, ahi.z, ahi.w};
            bfr[i] = (i32x8){blo.x, blo.y, blo.z, blo.w, bhi.x, bhi.y, bhi.z, bhi.w};
        }
#pragma unroll
        for (int i = 0; i < 4; ++i)
#pragma unroll
            for (int j = 0; j < 4; ++j)
                acc[i][j] = __builtin_amdgcn_mfma_scale_f32_16x16x128_f8f6f4(
                    af[i], bfr[j], acc[i][j], 0, 0, 0, SCL_ONE, 0, SCL_E);
        __syncthreads();
    }

    if (MODE == 1) {
#pragma unroll
        for (int i = 0; i < 4; ++i)
#pragma unroll
            for (int r = 0; r < 4; ++r) {
                const int c = m0 + wr * 64 + i * 16 + quad * 4 + r;
                const int t = c >> 6, o = c & 63;
#pragma unroll
                for (int j = 0; j < 4; ++j) {
                    const int n = n0 + wc * 64 + j * 16 + l15;
                    const size_t zi = ((size_t)b * TO + c) * NNODE + n;
                    const float z = bf2f(Qc[zi]) + 2.0f * acc[i][j][r];
                    Zf8[zi] = f2fp8(z);
                    ushort_t* p = Pbp + (((size_t)b * TT + t) * NNODE + n) * OO + o;
                    *p = f2bf(bf2f(*p) - z);
                }
            }
    } else {
#pragma unroll
        for (int i = 0; i < 4; ++i)
#pragma unroll
            for (int r = 0; r < 4; ++r) {
                const int n = m0 + wr * 64 + i * 16 + quad * 4 + r;
#pragma unroll
                for (int j = 0; j < 4; ++j) {
                    const int c = n0 + wc * 64 + j * 16 + l15;
                    const int t = c >> 6, o = c & 63;
                    const size_t id = (((size_t)b * TT + t) * NNODE + n) * OO + o;
                    outp[id] = fmaxf(bf2f(Pbp[id]) + acc[i][j][r], 0.0f);
                }
            }
    }
}

extern "C" void kernel_launch(void* const* d_in, const int* in_sizes, int n_in,
                              void* d_out, int out_size, void* d_ws, size_t ws_size,
                              hipStream_t stream) {
    const float* x = (const float*)d_in[0];
    const float* A = (const float*)d_in[1];
    const float* Th = (const float*)d_in[2];
    float* out = (float*)d_out;
    char* ws = (char*)d_ws;

    // workspace (~185 MiB)
    unsigned* lam = (unsigned*)ws;                                   // 256 B
    uchar_t* E8 = (uchar_t*)(ws + 256);                              // 32 MiB
    uchar_t* R2f8 = E8 + (size_t)NB * NNODE * NNODE;                 // 24 MiB
    uchar_t* Zf8 = R2f8 + (size_t)NB * TO * NNODE;                   // 24 MiB
    ushort_t* Qc = (ushort_t*)(Zf8 + (size_t)NB * TO * NNODE);       // 48 MiB
    ushort_t* Pb = Qc + (size_t)NB * TO * NNODE;                     // 48 MiB
    ushort_t* Tht = Pb + (size_t)NB * TT * NNODE * OO;               // 24 KiB

    k_init<<<1, 64, 0, stream>>>(lam);
    k_rowmax<<<512, 256, 0, stream>>>(A, lam);
    k_escale<<<16384, 256, 0, stream>>>(A, lam, E8);
    k_theta<<<48, 256, 0, stream>>>(Th, Tht);
    k_feature<<<dim3(8, 12, 32), 256, 0, stream>>>(x, Tht, Pb, Qc, R2f8);
    k_gemm8<1><<<dim3(6, 8, 32), 256, 0, stream>>>(R2f8, (size_t)TO * NNODE,
                                                   E8, (size_t)NNODE * NNODE,
                                                   Qc, Zf8, Pb, nullptr);
    k_gemm8<2><<<dim3(8, 6, 32), 256, 0, stream>>>(E8, (size_t)NNODE * NNODE,
                                                   Zf8, (size_t)TO * NNODE,
                                                   nullptr, nullptr, Pb, out);
}

// Round 4
// 496.519 us; speedup vs baseline: 1.2688x; 1.2688x over previous
//
#include <hip/hip_runtime.h>

typedef unsigned short ushort_t;
typedef unsigned char uchar_t;
typedef __attribute__((ext_vector_type(8))) __bf16 bf16x8;
typedef __attribute__((ext_vector_type(4))) float f32x4;
typedef __attribute__((ext_vector_type(8))) unsigned short u16x8;
typedef __attribute__((ext_vector_type(8))) int i32x8;

#define NB 32
#define TT 12
#define NNODE 1024
#define FF 64
#define OO 64
#define TO 768   // TT*OO

#define SCL_ONE 127   // e8m0 2^0
#define SCL_E   118   // e8m0 2^-9  (E stored pre-scaled by 2^9)

__device__ __forceinline__ unsigned short f2bf(float f) {
    unsigned u = __float_as_uint(f);
    u += 0x7FFFu + ((u >> 16) & 1u);           // RNE
    return (unsigned short)(u >> 16);
}
__device__ __forceinline__ float bf2f(unsigned short h) {
    return __uint_as_float(((unsigned)h) << 16);
}
__device__ __forceinline__ unsigned char f2fp8(float f) {
    return (unsigned char)(__builtin_amdgcn_cvt_pk_fp8_f32(f, f, 0, false) & 0xff);
}

// async global->LDS, 16B/lane; LDS dest = wave-uniform base + lane*16
__device__ __forceinline__ void gload16(const void* g, void* l) {
    __builtin_amdgcn_global_load_lds(
        (const __attribute__((address_space(1))) unsigned int*)g,
        (__attribute__((address_space(3))) unsigned int*)l, 16, 0, 0);
}

// ---------------------------------------------------------------- lambda init
__global__ void k_init(unsigned* lam) {
    if (threadIdx.x < NB) lam[threadIdx.x] = 0x3F800000u;  // 1.0f clamp
}

// ------------------------------------------------- lambda = max row-sum of A
__global__ __launch_bounds__(256) void k_rowmax(const float* __restrict__ A,
                                                unsigned* __restrict__ lam) {
    const int b = blockIdx.x >> 4;
    const int chunk = blockIdx.x & 15;
    const int w = threadIdx.x >> 6, lane = threadIdx.x & 63;
    const float* Ab = A + (size_t)b * NNODE * NNODE;
    float mx = 0.0f;
    for (int r = 0; r < 16; ++r) {
        const float* rp = Ab + (size_t)(chunk * 64 + w * 16 + r) * NNODE;
        float s = 0.0f;
#pragma unroll
        for (int j = 0; j < 16; ++j) s += rp[lane + j * 64];
#pragma unroll
        for (int off = 32; off > 0; off >>= 1) s += __shfl_down(s, off, 64);
        if (lane == 0) mx = fmaxf(mx, s);
    }
    if (lane == 0) atomicMax(&lam[b], __float_as_uint(mx));
}

// ----------------- E8[b][n][m] = fp8( A * 2^10 / lam )   (E = 2A/lam, x2^9)
__global__ __launch_bounds__(256) void k_escale(const float* __restrict__ A,
                                                const unsigned* __restrict__ lam,
                                                uchar_t* __restrict__ E8) {
    const size_t idx = ((size_t)blockIdx.x * 256 + threadIdx.x) * 8;
    const int b = (int)(idx >> 20);
    const float scl = 1024.0f / __uint_as_float(lam[b]);
    const float4 v0 = *(const float4*)(A + idx);
    const float4 v1 = *(const float4*)(A + idx + 4);
    unsigned lo = 0, hi = 0;
    lo = (unsigned)__builtin_amdgcn_cvt_pk_fp8_f32(v0.x * scl, v0.y * scl, (int)lo, false);
    lo = (unsigned)__builtin_amdgcn_cvt_pk_fp8_f32(v0.z * scl, v0.w * scl, (int)lo, true);
    hi = (unsigned)__builtin_amdgcn_cvt_pk_fp8_f32(v1.x * scl, v1.y * scl, (int)hi, false);
    hi = (unsigned)__builtin_amdgcn_cvt_pk_fp8_f32(v1.z * scl, v1.w * scl, (int)hi, true);
    uint2 pk; pk.x = lo; pk.y = hi;
    *(uint2*)(E8 + idx) = pk;
}

// ------------------------- Theta [3][64 f][64 o] fp32 -> Tht [3][64 o][64 f] bf16
__global__ void k_theta(const float* __restrict__ Th, ushort_t* __restrict__ Tht) {
    int tid = blockIdx.x * 256 + threadIdx.x;
    if (tid < 3 * 64 * 64) {
        int k = tid >> 12, rem = tid & 4095, o = rem >> 6, f = rem & 63;
        Tht[tid] = f2bf(Th[(k << 12) + (f << 6) + o]);
    }
}

// ----------------- feature transform: Rk = x@Theta_k  (bf16 MFMA / fp32 acc)
// writes: Pb[b,t,n,o]     = bf16(R0 - R2)      (row-major)
//         Qc[b][c][n]     = bf16(R1 - 2*R2)    (col-major, k=n contiguous)
//         R2f8[b][c][n]   = fp8(R2)            (col-major)
__global__ __launch_bounds__(256) void k_feature(const float* __restrict__ x,
                                                 const ushort_t* __restrict__ Tht,
                                                 ushort_t* __restrict__ Pb,
                                                 ushort_t* __restrict__ Qc,
                                                 uchar_t* __restrict__ R2f8) {
    __shared__ ushort_t xt[128 * 64];
    __shared__ ushort_t tb[64 * 136];   // bf16 transpose buf; reused as char (64*144)
    const int n0 = blockIdx.x * 128;
    const int t = blockIdx.y;
    const int b = blockIdx.z;
    const int tid = threadIdx.x;
    const int w = tid >> 6, lane = tid & 63, quad = lane >> 4, l15 = lane & 15;

    const float* xb = x + (((size_t)b * TT + t) * NNODE + n0) * FF;
#pragma unroll
    for (int i = 0; i < 8; ++i) {
        int q = i * 256 + tid;
        int row = q >> 4, fq = q & 15;
        const float4 v = *(const float4*)(xb + row * 64 + fq * 4);
        uint2 pk;
        pk.x = (unsigned)f2bf(v.x) | ((unsigned)f2bf(v.y) << 16);
        pk.y = (unsigned)f2bf(v.z) | ((unsigned)f2bf(v.w) << 16);
        *(uint2*)(xt + row * 64 + fq * 4) = pk;
    }
    __syncthreads();

    bf16x8 af[2][2];
#pragma unroll
    for (int rb = 0; rb < 2; ++rb)
#pragma unroll
        for (int ks = 0; ks < 2; ++ks)
            af[rb][ks] = *(const bf16x8*)(xt + (w * 32 + rb * 16 + l15) * 64 + ks * 32 + quad * 8);

    f32x4 acc[3][2][4];
#pragma unroll
    for (int k = 0; k < 3; ++k)
#pragma unroll
        for (int rb = 0; rb < 2; ++rb)
#pragma unroll
            for (int cb = 0; cb < 4; ++cb)
                acc[k][rb][cb] = (f32x4){0.f, 0.f, 0.f, 0.f};

#pragma unroll
    for (int k = 0; k < 3; ++k)
#pragma unroll
        for (int ks = 0; ks < 2; ++ks)
#pragma unroll
            for (int cb = 0; cb < 4; ++cb) {
                bf16x8 bfr = *(const bf16x8*)(Tht + ((size_t)(k * 64 + cb * 16 + l15)) * 64 + ks * 32 + quad * 8);
#pragma unroll
                for (int rb = 0; rb < 2; ++rb)
                    acc[k][rb][cb] = __builtin_amdgcn_mfma_f32_16x16x32_bf16(af[rb][ks], bfr, acc[k][rb][cb], 0, 0, 0);
            }

    // P = R0 - R2, row-major
    ushort_t* Pbb = Pb + (((size_t)b * TT + t) * NNODE + n0) * OO;
#pragma unroll
    for (int rb = 0; rb < 2; ++rb)
#pragma unroll
        for (int cb = 0; cb < 4; ++cb)
#pragma unroll
            for (int r = 0; r < 4; ++r) {
                int n = w * 32 + rb * 16 + quad * 4 + r;
                int o = cb * 16 + l15;
                Pbb[(size_t)n * OO + o] = f2bf(acc[0][rb][cb][r] - acc[2][rb][cb][r]);
            }

    {   // Q = R1 - 2*R2 (bf16, transposed to [c][n])  -- the inner-vector const term
#pragma unroll
        for (int rb = 0; rb < 2; ++rb)
#pragma unroll
            for (int cb = 0; cb < 4; ++cb)
#pragma unroll
                for (int r = 0; r < 4; ++r) {
                    int nl = w * 32 + rb * 16 + quad * 4 + r;
                    int o = cb * 16 + l15;
                    tb[o * 136 + nl] = f2bf(acc[1][rb][cb][r] - 2.0f * acc[2][rb][cb][r]);
                }
        __syncthreads();
        int o = tid >> 2, seg = tid & 3;
        ushort_t* drow = Qc + ((size_t)b * TO + t * 64 + o) * NNODE + n0 + seg * 32;
        const ushort_t* srow = tb + o * 136 + seg * 32;
#pragma unroll
        for (int i = 0; i < 4; ++i)
            *(u16x8*)(drow + i * 8) = *(const u16x8*)(srow + i * 8);
        __syncthreads();
    }
    {   // R2 (fp8, transposed to [c][n])
        char* tbc = (char*)tb;   // stride 144 bytes
#pragma unroll
        for (int rb = 0; rb < 2; ++rb)
#pragma unroll
            for (int cb = 0; cb < 4; ++cb)
#pragma unroll
                for (int r = 0; r < 4; ++r) {
                    int nl = w * 32 + rb * 16 + quad * 4 + r;
                    int o = cb * 16 + l15;
                    tbc[o * 144 + nl] = (char)f2fp8(acc[2][rb][cb][r]);
                }
        __syncthreads();
        int o = tid >> 2, seg = tid & 3;
        uchar_t* drow = R2f8 + ((size_t)b * TO + t * 64 + o) * NNODE + n0 + seg * 32;
        const char* srow = tbc + o * 144 + seg * 32;
        *(int4*)(drow) = *(const int4*)(srow);
        *(int4*)(drow + 16) = *(const int4*)(srow + 16);
    }
}

// ------------------------------------------------------------- MX-fp8 GEMM
// D[r][c] = sum_k Aop[b][r][k] * Bop[b][c][k], both fp8 k-contiguous,
// HW descale 2^-9 total (exactly one operand pre-scaled x2^9).
// 1-D grid, XCD swizzle: bid%8 = XCD; all 48 tiles of a batch on one XCD.
// MODE 1 (W build):  r=c (768 rows), c=n.  A=R2f8, B=E8.
//    w = Qc[c][n] + 2*D = R1 - 2R2 + 2*E@R2;  Zf8[c][n] = fp8(w);  Pb -= w
//    (Pb RMW goes through an LDS transpose -> fully coalesced 16B row RMW)
// MODE 2 (output):   r=n (1024 rows), c=c.    A=E8, B=Zf8.
//    out = relu(bf16(Pb) + D)    (Pb already holds P - W; D = E@W)
template <int MODE>
__global__ __launch_bounds__(256) void k_gemm8(const uchar_t* __restrict__ Aop, size_t aBS,
                                               const uchar_t* __restrict__ Bop, size_t bBS,
                                               const ushort_t* __restrict__ Qc,
                                               uchar_t* __restrict__ Zf8,
                                               ushort_t* __restrict__ Pbp,
                                               float* __restrict__ outp) {
    __shared__ __align__(16) uchar_t smem[34816];   // main loop: 2x16KB tiles; epilogue: 128x136 bf16
    uchar_t* At = smem;
    uchar_t* Bt = smem + 16384;
    const int bid = blockIdx.x;
    const int xcd = bid & 7, y = bid >> 3;
    const int tile = y % 48;
    const int b = xcd + 8 * (y / 48);
    const int tm = (MODE == 1) ? (tile >> 3) : (tile / 6);
    const int tn = (MODE == 1) ? (tile & 7) : (tile % 6);
    const int m0 = tm * 128, n0 = tn * 128;
    const int tid = threadIdx.x;
    const int w = tid >> 6, lane = tid & 63, quad = lane >> 4, l15 = lane & 15;
    const int wr = w >> 1, wc = w & 1;
    const uchar_t* Ab = Aop + (size_t)b * aBS + (size_t)m0 * NNODE;
    const uchar_t* Bb = Bop + (size_t)b * bBS + (size_t)n0 * NNODE;

    // staging: 16KB per tile, XOR-swizzled 16B chunks (phys = log ^ (row&7))
    int ldso[4];
    size_t goff[4];
#pragma unroll
    for (int i = 0; i < 4; ++i) {
        int slot = i * 256 + tid;
        int row = slot >> 3;
        int lc = (slot & 7) ^ (row & 7);
        ldso[i] = slot * 16;
        goff[i] = (size_t)row * NNODE + lc * 16;
    }

    f32x4 acc[4][4];
#pragma unroll
    for (int i = 0; i < 4; ++i)
#pragma unroll
        for (int j = 0; j < 4; ++j) acc[i][j] = (f32x4){0.f, 0.f, 0.f, 0.f};

    for (int kk = 0; kk < 8; ++kk) {
        const int k0 = kk << 7;
#pragma unroll
        for (int i = 0; i < 4; ++i) {
            gload16(Ab + k0 + goff[i], At + ldso[i]);
            gload16(Bb + k0 + goff[i], Bt + ldso[i]);
        }
        __syncthreads();
        i32x8 af[4], bfr[4];
#pragma unroll
        for (int i = 0; i < 4; ++i) {
            const int m = wr * 64 + i * 16 + l15;
            const int n = wc * 64 + i * 16 + l15;
            const int4 alo = *(const int4*)(At + m * 128 + (((quad << 1)) ^ (m & 7)) * 16);
            const int4 ahi = *(const int4*)(At + m * 128 + (((quad << 1) | 1) ^ (m & 7)) * 16);
            const int4 blo = *(const int4*)(Bt + n * 128 + (((quad << 1)) ^ (n & 7)) * 16);
            const int4 bhi = *(const int4*)(Bt + n * 128 + (((quad << 1) | 1) ^ (n & 7)) * 16);
            af[i] = (i32x8){alo.x, alo.y, alo.z, alo.w, ahi.x, ahi.y, ahi.z, ahi.w};
            bfr[i] = (i32x8){blo.x, blo.y, blo.z, blo.w, bhi.x, bhi.y, bhi.z, bhi.w};
        }
#pragma unroll
        for (int i = 0; i < 4; ++i)
#pragma unroll
            for (int j = 0; j < 4; ++j)
                acc[i][j] = __builtin_amdgcn_mfma_scale_f32_16x16x128_f8f6f4(
                    af[i], bfr[j], acc[i][j], 0, 0, 0, SCL_ONE, 0, SCL_E);
        __syncthreads();
    }

    if (MODE == 1) {
        ushort_t* tb = (ushort_t*)smem;   // [n_loc][c_loc], stride 136
        const ushort_t* Qb = Qc + (size_t)b * TO * NNODE;
        uchar_t* Zb = Zf8 + (size_t)b * TO * NNODE;
#pragma unroll
        for (int i = 0; i < 4; ++i)
#pragma unroll
            for (int r = 0; r < 4; ++r) {
                const int cl = wr * 64 + i * 16 + quad * 4 + r;
                const int c = m0 + cl;
#pragma unroll
                for (int j = 0; j < 4; ++j) {
                    const int nl = wc * 64 + j * 16 + l15;
                    const size_t zi = (size_t)c * NNODE + n0 + nl;
                    const float z = bf2f(Qb[zi]) + 2.0f * acc[i][j][r];
                    Zb[zi] = f2fp8(z);
                    tb[nl * 136 + cl] = f2bf(z);
                }
            }
        __syncthreads();
        // coalesced Pb -= w : each thread handles one (n-row, t-half) 128B segment
        const int t0 = m0 >> 6;
        const int row = tid >> 1, half = tid & 1;
        ushort_t* prow = Pbp + (((size_t)b * TT + t0 + half) * NNODE + n0 + row) * OO;
        const ushort_t* srow = tb + row * 136 + half * 64;
#pragma unroll
        for (int s = 0; s < 8; ++s) {
            u16x8 pv = *(const u16x8*)(prow + s * 8);
            u16x8 zv = *(const u16x8*)(srow + s * 8);
            u16x8 rv;
#pragma unroll
            for (int e = 0; e < 8; ++e) rv[e] = f2bf(bf2f(pv[e]) - bf2f(zv[e]));
            *(u16x8*)(prow + s * 8) = rv;
        }
    } else {
#pragma unroll
        for (int i = 0; i < 4; ++i)
#pragma unroll
            for (int r = 0; r < 4; ++r) {
                const int n = m0 + wr * 64 + i * 16 + quad * 4 + r;
#pragma unroll
                for (int j = 0; j < 4; ++j) {
                    const int c = n0 + wc * 64 + j * 16 + l15;
                    const int t = c >> 6, o = c & 63;
                    const size_t id = (((size_t)b * TT + t) * NNODE + n) * OO + o;
                    outp[id] = fmaxf(bf2f(Pbp[id]) + acc[i][j][r], 0.0f);
                }
            }
    }
}

extern "C" void kernel_launch(void* const* d_in, const int* in_sizes, int n_in,
                              void* d_out, int out_size, void* d_ws, size_t ws_size,
                              hipStream_t stream) {
    const float* x = (const float*)d_in[0];
    const float* A = (const float*)d_in[1];
    const float* Th = (const float*)d_in[2];
    float* out = (float*)d_out;
    char* ws = (char*)d_ws;

    // workspace (~176 MiB)
    unsigned* lam = (unsigned*)ws;                                   // 256 B
    uchar_t* E8 = (uchar_t*)(ws + 256);                              // 32 MiB
    uchar_t* R2f8 = E8 + (size_t)NB * NNODE * NNODE;                 // 24 MiB
    uchar_t* Zf8 = R2f8 + (size_t)NB * TO * NNODE;                   // 24 MiB
    ushort_t* Qc = (ushort_t*)(Zf8 + (size_t)NB * TO * NNODE);       // 48 MiB
    ushort_t* Pb = Qc + (size_t)NB * TO * NNODE;                     // 48 MiB
    ushort_t* Tht = Pb + (size_t)NB * TT * NNODE * OO;               // 24 KiB

    k_init<<<1, 64, 0, stream>>>(lam);
    k_rowmax<<<512, 256, 0, stream>>>(A, lam);
    k_escale<<<16384, 256, 0, stream>>>(A, lam, E8);
    k_theta<<<48, 256, 0, stream>>>(Th, Tht);
    k_feature<<<dim3(8, 12, 32), 256, 0, stream>>>(x, Tht, Pb, Qc, R2f8);
    k_gemm8<1><<<1536, 256, 0, stream>>>(R2f8, (size_t)TO * NNODE,
                                         E8, (size_t)NNODE * NNODE,
                                         Qc, Zf8, Pb, nullptr);
    k_gemm8<2><<<1536, 256, 0, stream>>>(E8, (size_t)NNODE * NNODE,
                                         Zf8, (size_t)TO * NNODE,
                                         nullptr, nullptr, Pb, out);
}

// Round 5
// 465.577 us; speedup vs baseline: 1.3531x; 1.0665x over previous
//
#include <hip/hip_runtime.h>

typedef unsigned short ushort_t;
typedef unsigned char uchar_t;
typedef __attribute__((ext_vector_type(8))) __bf16 bf16x8;
typedef __attribute__((ext_vector_type(4))) float f32x4;
typedef __attribute__((ext_vector_type(8))) unsigned short u16x8;
typedef __attribute__((ext_vector_type(8))) int i32x8;

#define NB 32
#define TT 12
#define NNODE 1024
#define FF 64
#define OO 64
#define TO 768   // TT*OO

#define SCL_ONE 127   // e8m0 2^0
#define SCL_E   118   // e8m0 2^-9  (E stored pre-scaled by 2^9)

__device__ __forceinline__ unsigned short f2bf(float f) {
    unsigned u = __float_as_uint(f);
    u += 0x7FFFu + ((u >> 16) & 1u);           // RNE
    return (unsigned short)(u >> 16);
}
__device__ __forceinline__ float bf2f(unsigned short h) {
    return __uint_as_float(((unsigned)h) << 16);
}
__device__ __forceinline__ unsigned char f2fp8(float f) {
    return (unsigned char)(__builtin_amdgcn_cvt_pk_fp8_f32(f, f, 0, false) & 0xff);
}

// async global->LDS, 16B/lane; LDS dest = wave-uniform base + lane*16
__device__ __forceinline__ void gload16(const void* g, void* l) {
    __builtin_amdgcn_global_load_lds(
        (const __attribute__((address_space(1))) unsigned int*)g,
        (__attribute__((address_space(3))) unsigned int*)l, 16, 0, 0);
}

// ---------------------------------------------------------------- lambda init
__global__ void k_init(unsigned* lam) {
    if (threadIdx.x < NB) lam[threadIdx.x] = 0x3F800000u;  // 1.0f clamp
}

// ------------------------------------------------- lambda = max row-sum of A
__global__ __launch_bounds__(256) void k_rowmax(const float* __restrict__ A,
                                                unsigned* __restrict__ lam) {
    const int b = blockIdx.x >> 4;
    const int chunk = blockIdx.x & 15;
    const int w = threadIdx.x >> 6, lane = threadIdx.x & 63;
    const float* Ab = A + (size_t)b * NNODE * NNODE;
    float mx = 0.0f;
    for (int r = 0; r < 16; ++r) {
        const float* rp = Ab + (size_t)(chunk * 64 + w * 16 + r) * NNODE;
        float s = 0.0f;
#pragma unroll
        for (int j = 0; j < 16; ++j) s += rp[lane + j * 64];
#pragma unroll
        for (int off = 32; off > 0; off >>= 1) s += __shfl_down(s, off, 64);
        if (lane == 0) mx = fmaxf(mx, s);
    }
    if (lane == 0) atomicMax(&lam[b], __float_as_uint(mx));
}

// ----------------- E8[b][n][m] = fp8( A * 2^10 / lam )   (E = 2A/lam, x2^9)
__global__ __launch_bounds__(256) void k_escale(const float* __restrict__ A,
                                                const unsigned* __restrict__ lam,
                                                uchar_t* __restrict__ E8) {
    const size_t idx = ((size_t)blockIdx.x * 256 + threadIdx.x) * 8;
    const int b = (int)(idx >> 20);
    const float scl = 1024.0f / __uint_as_float(lam[b]);
    const float4 v0 = *(const float4*)(A + idx);
    const float4 v1 = *(const float4*)(A + idx + 4);
    unsigned lo = 0, hi = 0;
    lo = (unsigned)__builtin_amdgcn_cvt_pk_fp8_f32(v0.x * scl, v0.y * scl, (int)lo, false);
    lo = (unsigned)__builtin_amdgcn_cvt_pk_fp8_f32(v0.z * scl, v0.w * scl, (int)lo, true);
    hi = (unsigned)__builtin_amdgcn_cvt_pk_fp8_f32(v1.x * scl, v1.y * scl, (int)hi, false);
    hi = (unsigned)__builtin_amdgcn_cvt_pk_fp8_f32(v1.z * scl, v1.w * scl, (int)hi, true);
    uint2 pk; pk.x = lo; pk.y = hi;
    *(uint2*)(E8 + idx) = pk;
}

// ------------------------- Theta [3][64 f][64 o] fp32 -> Tht [3][64 o][64 f] bf16
__global__ void k_theta(const float* __restrict__ Th, ushort_t* __restrict__ Tht) {
    int tid = blockIdx.x * 256 + threadIdx.x;
    if (tid < 3 * 64 * 64) {
        int k = tid >> 12, rem = tid & 4095, o = rem >> 6, f = rem & 63;
        Tht[tid] = f2bf(Th[(k << 12) + (f << 6) + o]);
    }
}

// ----------------- feature transform: Rk = x@Theta_k  (bf16 MFMA / fp32 acc)
// 512 threads, 128-node tile. Theta in LDS (swizzled), x direct from global.
// writes: Pb[b,t,n,o]     = bf16(R0 - R2)      (row-major)
//         Qc[b][c][n]     = bf16(R1 - 2*R2)    (col-major, k=n contiguous)
//         R2f8[b][c][n]   = fp8(R2)            (col-major)
__global__ __launch_bounds__(512, 5) void k_feature(const float* __restrict__ x,
                                                    const ushort_t* __restrict__ Tht,
                                                    ushort_t* __restrict__ Pb,
                                                    ushort_t* __restrict__ Qc,
                                                    uchar_t* __restrict__ R2f8) {
    __shared__ __align__(16) uchar_t th[3 * 64 * 128];    // 24576 B, [ko][f], 16B-chunk swizzled
    __shared__ __align__(16) uchar_t tbuf[26624];         // Q: 64*136 u16 (17408) + R2: 64*144 u8 (9216)
    ushort_t* tbq = (ushort_t*)tbuf;
    char* tbr = (char*)(tbuf + 17408);

    const int n0 = blockIdx.x * 128;
    const int t = blockIdx.y;
    const int b = blockIdx.z;
    const int tid = threadIdx.x;
    const int w = tid >> 6, lane = tid & 63, quad = lane >> 4, l15 = lane & 15;

    // Theta -> LDS, 16B chunks, phys chunk = c ^ (row&7) to break l15-stride-128B aliasing
#pragma unroll
    for (int i = 0; i < 3; ++i) {
        int chunk = i * 512 + tid;            // 0..1535
        int ko = chunk >> 3, c = chunk & 7;
        int phys = c ^ (ko & 7);
        const int4 v = *(const int4*)(Tht + ko * 64 + c * 8);
        *(int4*)(th + ko * 128 + phys * 16) = v;
    }

    // A-frags straight from global (row = n0 + w*16 + l15), fp32 -> bf16 in regs
    const float* xr = x + (((size_t)b * TT + t) * NNODE + n0 + w * 16 + l15) * FF;
    bf16x8 af[2];
#pragma unroll
    for (int ks = 0; ks < 2; ++ks) {
        const float4 v0 = *(const float4*)(xr + ks * 32 + quad * 8);
        const float4 v1 = *(const float4*)(xr + ks * 32 + quad * 8 + 4);
        u16x8 p;
        p[0] = f2bf(v0.x); p[1] = f2bf(v0.y); p[2] = f2bf(v0.z); p[3] = f2bf(v0.w);
        p[4] = f2bf(v1.x); p[5] = f2bf(v1.y); p[6] = f2bf(v1.z); p[7] = f2bf(v1.w);
        af[ks] = *(bf16x8*)&p;
    }
    __syncthreads();

    f32x4 acc[3][4];
#pragma unroll
    for (int k = 0; k < 3; ++k)
#pragma unroll
        for (int cb = 0; cb < 4; ++cb) acc[k][cb] = (f32x4){0.f, 0.f, 0.f, 0.f};

#pragma unroll
    for (int k = 0; k < 3; ++k)
#pragma unroll
        for (int ks = 0; ks < 2; ++ks)
#pragma unroll
            for (int cb = 0; cb < 4; ++cb) {
                const int o = cb * 16 + l15;
                const int c = (ks * 4 + quad) ^ (o & 7);
                const bf16x8 bfr = *(const bf16x8*)(th + (k * 64 + o) * 128 + c * 16);
                acc[k][cb] = __builtin_amdgcn_mfma_f32_16x16x32_bf16(af[ks], bfr, acc[k][cb], 0, 0, 0);
            }

    // P = R0 - R2, row-major (16 x 2B stores/lane, 32B segments per l15-group)
    ushort_t* Pbb = Pb + (((size_t)b * TT + t) * NNODE + n0) * OO;
#pragma unroll
    for (int cb = 0; cb < 4; ++cb)
#pragma unroll
        for (int r = 0; r < 4; ++r) {
            const int n = w * 16 + quad * 4 + r;
            const int o = cb * 16 + l15;
            Pbb[(size_t)n * OO + o] = f2bf(acc[0][cb][r] - acc[2][cb][r]);
        }

    // Q and R2 transposes, single LDS phase
#pragma unroll
    for (int cb = 0; cb < 4; ++cb)
#pragma unroll
        for (int r = 0; r < 4; ++r) {
            const int nl = w * 16 + quad * 4 + r;
            const int o = cb * 16 + l15;
            tbq[o * 136 + nl] = f2bf(acc[1][cb][r] - 2.0f * acc[2][cb][r]);
            tbr[o * 144 + nl] = (char)f2fp8(acc[2][cb][r]);
        }
    __syncthreads();

    {   // stream out: 8 threads per o-row
        const int o = tid >> 3, seg = tid & 7;
        ushort_t* qrow = Qc + ((size_t)b * TO + t * 64 + o) * NNODE + n0 + seg * 16;
        const ushort_t* sq = tbq + o * 136 + seg * 16;
        *(u16x8*)(qrow) = *(const u16x8*)(sq);
        *(u16x8*)(qrow + 8) = *(const u16x8*)(sq + 8);
        uchar_t* rrow = R2f8 + ((size_t)b * TO + t * 64 + o) * NNODE + n0 + seg * 16;
        *(int4*)rrow = *(const int4*)(tbr + o * 144 + seg * 16);
    }
}

// ------------------------------------------------------------- MX-fp8 GEMM
// D[r][c] = sum_k Aop[b][r][k] * Bop[b][c][k], both fp8 k-contiguous,
// HW descale 2^-9 total (exactly one operand pre-scaled x2^9).
// 1-D grid, XCD swizzle: bid%8 = XCD; all 48 tiles of a batch on one XCD.
// MODE 1 (W build):  r=c (768 rows), c=n.  A=R2f8, B=E8.
//    w = Qc[c][n] + 2*D = R1 - 2R2 + 2*E@R2;  Zf8[c][n] = fp8(w);  Pb -= w
//    (Pb RMW goes through an LDS transpose -> fully coalesced 16B row RMW)
// MODE 2 (output):   r=n (1024 rows), c=c.    A=E8, B=Zf8.
//    out = relu(bf16(Pb) + D)    (Pb already holds P - W; D = E@W)
template <int MODE>
__global__ __launch_bounds__(256) void k_gemm8(const uchar_t* __restrict__ Aop, size_t aBS,
                                               const uchar_t* __restrict__ Bop, size_t bBS,
                                               const ushort_t* __restrict__ Qc,
                                               uchar_t* __restrict__ Zf8,
                                               ushort_t* __restrict__ Pbp,
                                               float* __restrict__ outp) {
    __shared__ __align__(16) uchar_t smem[34816];   // main loop: 2x16KB tiles; epilogue: 128x136 bf16
    uchar_t* At = smem;
    uchar_t* Bt = smem + 16384;
    const int bid = blockIdx.x;
    const int xcd = bid & 7, y = bid >> 3;
    const int tile = y % 48;
    const int b = xcd + 8 * (y / 48);
    const int tm = (MODE == 1) ? (tile >> 3) : (tile / 6);
    const int tn = (MODE == 1) ? (tile & 7) : (tile % 6);
    const int m0 = tm * 128, n0 = tn * 128;
    const int tid = threadIdx.x;
    const int w = tid >> 6, lane = tid & 63, quad = lane >> 4, l15 = lane & 15;
    const int wr = w >> 1, wc = w & 1;
    const uchar_t* Ab = Aop + (size_t)b * aBS + (size_t)m0 * NNODE;
    const uchar_t* Bb = Bop + (size_t)b * bBS + (size_t)n0 * NNODE;

    // staging: 16KB per tile, XOR-swizzled 16B chunks (phys = log ^ (row&7))
    int ldso[4];
    size_t goff[4];
#pragma unroll
    for (int i = 0; i < 4; ++i) {
        int slot = i * 256 + tid;
        int row = slot >> 3;
        int lc = (slot & 7) ^ (row & 7);
        ldso[i] = slot * 16;
        goff[i] = (size_t)row * NNODE + lc * 16;
    }

    f32x4 acc[4][4];
#pragma unroll
    for (int i = 0; i < 4; ++i)
#pragma unroll
        for (int j = 0; j < 4; ++j) acc[i][j] = (f32x4){0.f, 0.f, 0.f, 0.f};

    for (int kk = 0; kk < 8; ++kk) {
        const int k0 = kk << 7;
#pragma unroll
        for (int i = 0; i < 4; ++i) {
            gload16(Ab + k0 + goff[i], At + ldso[i]);
            gload16(Bb + k0 + goff[i], Bt + ldso[i]);
        }
        __syncthreads();
        i32x8 af[4], bfr[4];
#pragma unroll
        for (int i = 0; i < 4; ++i) {
            const int m = wr * 64 + i * 16 + l15;
            const int n = wc * 64 + i * 16 + l15;
            const int4 alo = *(const int4*)(At + m * 128 + (((quad << 1)) ^ (m & 7)) * 16);
            const int4 ahi = *(const int4*)(At + m * 128 + (((quad << 1) | 1) ^ (m & 7)) * 16);
            const int4 blo = *(const int4*)(Bt + n * 128 + (((quad << 1)) ^ (n & 7)) * 16);
            const int4 bhi = *(const int4*)(Bt + n * 128 + (((quad << 1) | 1) ^ (n & 7)) * 16);
            af[i] = (i32x8){alo.x, alo.y, alo.z, alo.w, ahi.x, ahi.y, ahi.z, ahi.w};
            bfr[i] = (i32x8){blo.x, blo.y, blo.z, blo.w, bhi.x, bhi.y, bhi.z, bhi.w};
        }
#pragma unroll
        for (int i = 0; i < 4; ++i)
#pragma unroll
            for (int j = 0; j < 4; ++j)
                acc[i][j] = __builtin_amdgcn_mfma_scale_f32_16x16x128_f8f6f4(
                    af[i], bfr[j], acc[i][j], 0, 0, 0, SCL_ONE, 0, SCL_E);
        __syncthreads();
    }

    if (MODE == 1) {
        ushort_t* tb = (ushort_t*)smem;   // [n_loc][c_loc], stride 136
        const ushort_t* Qb = Qc + (size_t)b * TO * NNODE;
        uchar_t* Zb = Zf8 + (size_t)b * TO * NNODE;
#pragma unroll
        for (int i = 0; i < 4; ++i)
#pragma unroll
            for (int r = 0; r < 4; ++r) {
                const int cl = wr * 64 + i * 16 + quad * 4 + r;
                const int c = m0 + cl;
#pragma unroll
                for (int j = 0; j < 4; ++j) {
                    const int nl = wc * 64 + j * 16 + l15;
                    const size_t zi = (size_t)c * NNODE + n0 + nl;
                    const float z = bf2f(Qb[zi]) + 2.0f * acc[i][j][r];
                    Zb[zi] = f2fp8(z);
                    tb[nl * 136 + cl] = f2bf(z);
                }
            }
        __syncthreads();
        // coalesced Pb -= w : each thread handles one (n-row, t-half) 128B segment
        const int t0 = m0 >> 6;
        const int row = tid >> 1, half = tid & 1;
        ushort_t* prow = Pbp + (((size_t)b * TT + t0 + half) * NNODE + n0 + row) * OO;
        const ushort_t* srow = tb + row * 136 + half * 64;
#pragma unroll
        for (int s = 0; s < 8; ++s) {
            u16x8 pv = *(const u16x8*)(prow + s * 8);
            u16x8 zv = *(const u16x8*)(srow + s * 8);
            u16x8 rv;
#pragma unroll
            for (int e = 0; e < 8; ++e) rv[e] = f2bf(bf2f(pv[e]) - bf2f(zv[e]));
            *(u16x8*)(prow + s * 8) = rv;
        }
    } else {
#pragma unroll
        for (int i = 0; i < 4; ++i)
#pragma unroll
            for (int r = 0; r < 4; ++r) {
                const int n = m0 + wr * 64 + i * 16 + quad * 4 + r;
#pragma unroll
                for (int j = 0; j < 4; ++j) {
                    const int c = n0 + wc * 64 + j * 16 + l15;
                    const int t = c >> 6, o = c & 63;
                    const size_t id = (((size_t)b * TT + t) * NNODE + n) * OO + o;
                    outp[id] = fmaxf(bf2f(Pbp[id]) + acc[i][j][r], 0.0f);
                }
            }
    }
}

extern "C" void kernel_launch(void* const* d_in, const int* in_sizes, int n_in,
                              void* d_out, int out_size, void* d_ws, size_t ws_size,
                              hipStream_t stream) {
    const float* x = (const float*)d_in[0];
    const float* A = (const float*)d_in[1];
    const float* Th = (const float*)d_in[2];
    float* out = (float*)d_out;
    char* ws = (char*)d_ws;

    // workspace (~176 MiB)
    unsigned* lam = (unsigned*)ws;                                   // 256 B
    uchar_t* E8 = (uchar_t*)(ws + 256);                              // 32 MiB
    uchar_t* R2f8 = E8 + (size_t)NB * NNODE * NNODE;                 // 24 MiB
    uchar_t* Zf8 = R2f8 + (size_t)NB * TO * NNODE;                   // 24 MiB
    ushort_t* Qc = (ushort_t*)(Zf8 + (size_t)NB * TO * NNODE);       // 48 MiB
    ushort_t* Pb = Qc + (size_t)NB * TO * NNODE;                     // 48 MiB
    ushort_t* Tht = Pb + (size_t)NB * TT * NNODE * OO;               // 24 KiB

    k_init<<<1, 64, 0, stream>>>(lam);
    k_rowmax<<<512, 256, 0, stream>>>(A, lam);
    k_escale<<<16384, 256, 0, stream>>>(A, lam, E8);
    k_theta<<<48, 256, 0, stream>>>(Th, Tht);
    k_feature<<<dim3(8, 12, 32), 512, 0, stream>>>(x, Tht, Pb, Qc, R2f8);
    k_gemm8<1><<<1536, 256, 0, stream>>>(R2f8, (size_t)TO * NNODE,
                                         E8, (size_t)NNODE * NNODE,
                                         Qc, Zf8, Pb, nullptr);
    k_gemm8<2><<<1536, 256, 0, stream>>>(E8, (size_t)NNODE * NNODE,
                                         Zf8, (size_t)TO * NNODE,
                                         nullptr, nullptr, Pb, out);
}